// Round 6
// baseline (189.720 us; speedup 1.0000x reference)
//
#include <hip/hip_runtime.h>
#include <math.h>

#define NH      6
#define T_IN    2000
#define T_AUD   960000
#define NB      4
#define C_IN    129
#define C_MID   32
#define CSPLIT  3
#define NC_PER  43          // channels per c-split (43*3 = 129)
#define SPLIT_STRIDE (NB * C_MID * T_IN)   // 256000 floats

typedef float f4 __attribute__((ext_vector_type(4)));

// ---------------- conv1 partials (no bias), split over channels ----------------
// grid: x = 8 t-tiles, y = b*4 + og (16), z = csplit (3). block 256.
__global__ void k_conv1(const float* __restrict__ f0, const float* __restrict__ mel,
                        const float* __restrict__ w1, float* __restrict__ hpart) {
    const int t0  = blockIdx.x * 256;
    const int b   = blockIdx.y >> 2;
    const int o0  = (blockIdx.y & 3) * 8;
    const int z   = blockIdx.z;
    const int cbase = z * NC_PER;
    const int tid = threadIdx.x;

    __shared__ float xl[NC_PER][264];   // staged cols [t0-4, t0+260)

    for (int idx = tid; idx < NC_PER * 66; idx += 256) {
        const int r = idx / 66;
        const int j = idx - r * 66;
        const int c = cbase + r;
        const float* row = (c == 0) ? (f0 + b * T_IN)
                                    : (mel + ((size_t)(b * 128 + (c - 1))) * T_IN);
        const int gt = t0 - 4 + j * 4;
        float4 v;
        if (gt >= 0 && gt + 3 < T_IN) {
            v = *(const float4*)(row + gt);
        } else {
            v.x = (gt + 0 >= 0 && gt + 0 < T_IN) ? row[gt + 0] : 0.0f;
            v.y = (gt + 1 >= 0 && gt + 1 < T_IN) ? row[gt + 1] : 0.0f;
            v.z = (gt + 2 >= 0 && gt + 2 < T_IN) ? row[gt + 2] : 0.0f;
            v.w = (gt + 3 >= 0 && gt + 3 < T_IN) ? row[gt + 3] : 0.0f;
        }
        *(float4*)(&xl[r][j * 4]) = v;
    }
    __syncthreads();

    float acc[8];
    #pragma unroll
    for (int oo = 0; oo < 8; ++oo) acc[oo] = 0.0f;

    for (int c = 0; c < NC_PER; ++c) {
        const float x0 = xl[c][tid + 2];
        const float x1 = xl[c][tid + 3];
        const float x2 = xl[c][tid + 4];
        const float x3 = xl[c][tid + 5];
        const float x4 = xl[c][tid + 6];
        const int cg = cbase + c;
        #pragma unroll
        for (int oo = 0; oo < 8; ++oo) {
            const float* wp = w1 + (size_t)(o0 + oo) * (C_IN * 5) + cg * 5;  // wave-uniform -> scalar
            acc[oo] = fmaf(wp[0], x0, acc[oo]);
            acc[oo] = fmaf(wp[1], x1, acc[oo]);
            acc[oo] = fmaf(wp[2], x2, acc[oo]);
            acc[oo] = fmaf(wp[3], x3, acc[oo]);
            acc[oo] = fmaf(wp[4], x4, acc[oo]);
        }
    }

    const int t = t0 + tid;
    if (t < T_IN) {
        #pragma unroll
        for (int oo = 0; oo < 8; ++oo)
            hpart[(size_t)z * SPLIT_STRIDE + ((size_t)(b * C_MID + o0 + oo)) * T_IN + t] = acc[oo];
    }
}

// =====================================================================
// k_main2: inline conv2 + inline frame-prefix + closed-form phase + harmonics.
// grid (938, NB), block 256, 4 consecutive samples/thread (block tile 1024).
// E(t)/48000 = Pfrac[i] + (n*f0[i] + d*W(n))/48000, n = t - 480*i - 239,
// W(n) = 0 (n<=0) | n^2/960 (n<=480) | n-240 (n>480)
// P[i] = 240*f0[0] + 240*sum_{j<i}(f0[j]+f0[j+1])  (f64, per-block reduction)
// Output stores are nontemporal (write-once, 107 MB).
// =====================================================================
__global__ __launch_bounds__(256) void k_main2(
        const float* __restrict__ f0, const float* __restrict__ noise,
        const float* __restrict__ hpart,
        const float* __restrict__ b1, const float* __restrict__ w2,
        const float* __restrict__ b2,
        const float* __restrict__ amp_logscale, const float* __restrict__ phase_offset,
        const float* __restrict__ lnv, const float* __restrict__ lnu,
        float* __restrict__ out) {
    const int b   = blockIdx.y;
    const int tid = threadIdx.x;
    const int s0  = blockIdx.x * 1024;
    const int t0  = s0 + tid * 4;

    __shared__ float  sf0[6];       // f0[i_lo .. i_lo+5] (clamped)
    __shared__ float  sPf[4];       // frac(P[i]/48000), i_lo..i_lo+3
    __shared__ float  smid[C_MID][5];  // silu(conv1+bias) at positions i_lo..i_lo+4
    __shared__ float  sam[NH][5];   // amp rows
    __shared__ float  sasc2[NH], soff[NH], snv, snu;
    __shared__ double swsum[4];

    // block-uniform lowest frame index
    const int ulo  = (s0 - 240) < 0 ? 0 : (s0 - 240);
    int i_lo = (unsigned)ulo / 480u;
    if (i_lo > 1998) i_lo = 1998;

    const float* f0b = f0 + b * T_IN;

    // ---- prefix partial: S = sum_{j < i_lo} (f0[j] + f0[j+1]) ----
    double S = 0.0;
    for (int j = tid; j < i_lo; j += 256)
        S += (double)f0b[j] + (double)f0b[j + 1];
    #pragma unroll
    for (int d = 32; d >= 1; d >>= 1) S += __shfl_down(S, d, 64);
    if ((tid & 63) == 0) swsum[tid >> 6] = S;

    // ---- stage sf0 + constants + smid (silu of conv1 sums) ----
    if (tid < 6) {
        int idx = i_lo + tid; if (idx > 1999) idx = 1999;
        sf0[tid] = f0b[idx];
    } else if (tid >= 8 && tid < 14) {
        sasc2[tid - 8] = 2.0f * __expf(amp_logscale[tid - 8]);
    } else if (tid >= 16 && tid < 22) {
        soff[tid - 16] = phase_offset[tid - 16];
    } else if (tid == 22) {
        snv = __expf(lnv[0]);
    } else if (tid == 23) {
        snu = __expf(lnu[0]);
    } else if (tid >= 32 && tid < 32 + C_MID * 5) {
        const int r  = tid - 32;
        const int o  = r / 5;
        const int jj = r - o * 5;
        int idx = i_lo + jj; if (idx > 1999) idx = 1999;
        const size_t base = ((size_t)(b * C_MID + o)) * T_IN + idx;
        const float v = hpart[base] + hpart[SPLIT_STRIDE + base]
                      + hpart[2 * SPLIT_STRIDE + base] + b1[o];
        smid[o][jj] = v * __builtin_amdgcn_rcpf(1.0f + __expf(-v));
    }
    __syncthreads();

    // ---- conv2 (1x1, 32->6) at the 5 positions ----
    if (tid < NH * 5) {
        const int h  = tid / 5;
        const int jj = tid - h * 5;
        float a = b2[h];
        #pragma unroll
        for (int o = 0; o < C_MID; ++o)
            a = fmaf(w2[h * C_MID + o], smid[o][jj], a);
        sam[h][jj] = a;
    }
    // ---- Pfrac recurrence (thread 32, f64) ----
    if (tid == 32) {
        double P = 240.0 * (double)f0b[0]
                 + 240.0 * (swsum[0] + swsum[1] + swsum[2] + swsum[3]);
        #pragma unroll
        for (int k = 0; k < 4; ++k) {
            const double q = P * (1.0 / 48000.0);
            sPf[k] = (float)(q - floor(q));
            P += 240.0 * ((double)sf0[k] + (double)sf0[k + 1]);
        }
    }
    __syncthreads();

    if (t0 >= T_AUD) return;

    const float inv48k = 1.0f / 48000.0f;
    float ph[4], wd[4], f0f[4], voiced[4];
    int li[4];
    #pragma unroll
    for (int j = 0; j < 4; ++j) {
        const int t = t0 + j;
        const int u = (t - 240) < 0 ? 0 : (t - 240);
        int i = (unsigned)u / 480u;
        if (i > 1998) i = 1998;
        li[j] = i - i_lo;
        const int m = t - i * 480 - 240;      // [-240, 719]
        const int n = m + 1;
        const float nf = (float)n;
        const float Wn = (n <= 0) ? 0.0f
                       : ((n <= 480) ? nf * nf * (1.0f / 960.0f) : nf - 240.0f);
        const float fa = sf0[li[j]];
        const float fd = sf0[li[j] + 1] - fa;
        const float pr = sPf[li[j]] + (nf * fa + fd * Wn) * inv48k;
        ph[j] = pr - floorf(pr);

        float w = ((float)m + 0.5f) * (1.0f / 480.0f);
        w = w < 0.0f ? 0.0f : (w > 1.0f ? 1.0f : w);
        wd[j] = w;
        f0f[j] = fmaf(fd, w, fa);
        voiced[j] = (f0f[j] > 1.0f) ? 1.0f : 0.0f;
    }

    const size_t outb = (size_t)b * 7 * T_AUD;
    #pragma unroll
    for (int h = 0; h < NH; ++h) {
        const float kf = (float)(h + 1);
        const float ascale2 = sasc2[h];
        const float off = soff[h];
        float r[4];
        #pragma unroll
        for (int j = 0; j < 4; ++j) {
            const float a0 = sam[h][li[j]];
            const float am = fmaf(sam[h][li[j] + 1] - a0, wd[j], a0);
            const float sig = __builtin_amdgcn_rcpf(1.0f + __expf(-am));
            const float arg = kf * ph[j] + off;            // revolutions
            const float fr  = arg - floorf(arg);
            const float sn  = __builtin_amdgcn_sinf(fr);   // sin(2*pi*fr)
            // anti-alias sigmoid: arg >= 17.5 for all f0<=500,k<=6 -> exactly 1.0f
            const float aaarg = (24000.0f - kf * f0f[j]) * (1.0f / 1200.0f);
            float aa = 1.0f;
            if (aaarg < 16.0f)   // wave-uniformly false in practice -> execz skip
                aa = __builtin_amdgcn_rcpf(1.0f + __expf(-aaarg));
            r[j] = sn * ascale2 * sig * (aa * voiced[j]);
        }
        f4 res; res.x = r[0]; res.y = r[1]; res.z = r[2]; res.w = r[3];
        __builtin_nontemporal_store(res, (f4*)(out + outb + (size_t)h * T_AUD + t0));
    }

    const f4 nz = __builtin_nontemporal_load((const f4*)(noise + (size_t)b * T_AUD + t0));
    f4 no;
    no.x = nz.x * (voiced[0] > 0.0f ? snv : snu);
    no.y = nz.y * (voiced[1] > 0.0f ? snv : snu);
    no.z = nz.z * (voiced[2] > 0.0f ? snv : snu);
    no.w = nz.w * (voiced[3] > 0.0f ? snv : snu);
    __builtin_nontemporal_store(no, (f4*)(out + outb + (size_t)6 * T_AUD + t0));
}

extern "C" void kernel_launch(void* const* d_in, const int* in_sizes, int n_in,
                              void* d_out, int out_size, void* d_ws, size_t ws_size,
                              hipStream_t stream) {
    const float* f0   = (const float*)d_in[0];
    const float* mel  = (const float*)d_in[1];
    const float* nois = (const float*)d_in[2];
    const float* w1   = (const float*)d_in[3];
    const float* b1   = (const float*)d_in[4];
    const float* w2   = (const float*)d_in[5];
    const float* b2   = (const float*)d_in[6];
    const float* alog = (const float*)d_in[7];
    const float* poff = (const float*)d_in[8];
    const float* lnv  = (const float*)d_in[9];
    const float* lnu  = (const float*)d_in[10];
    float* out = (float*)d_out;

    // workspace: hpart 3*4*32*2000 f32 (3072000 B)
    float* hpart = (float*)d_ws;

    k_conv1<<<dim3(8, 16, CSPLIT), 256, 0, stream>>>(f0, mel, w1, hpart);
    k_main2<<<dim3((T_AUD + 1023) / 1024, NB), 256, 0, stream>>>(
        f0, nois, hpart, b1, w2, b2, alog, poff, lnv, lnu, out);
}